// Round 1
// baseline (470.077 us; speedup 1.0000x reference)
//
#include <hip/hip_runtime.h>
#include <math.h>

constexpr int Bb = 64, Nn = 512, Vv = 64, Hh = 512, Rr = 4, Aa = 18, INp = 128, KTOP = 32;
constexpr int CIN = 384;   // IN + R*V
constexpr int ROo = 68;    // V+4
constexpr int WOUT = 195;  // 3V+3
#define EPSf 1e-8f

__device__ __forceinline__ float sigmoidf(float x){ return 1.f/(1.f+expf(-x)); }
__device__ __forceinline__ float softplusf(float x){ return (x>20.f)? x : log1pf(expf(x)); }
__device__ __forceinline__ float wave_reduce(float v){
  #pragma unroll
  for(int o=32;o>0;o>>=1) v += __shfl_down(v, o, 64);
  return v;
}

// ---- 1. ro = W_read @ h + b_read ; one wave per (b, r*68+o) output ----
__global__ void k_read_proj(const float* __restrict__ Wr, const float* __restrict__ br,
                            const float* __restrict__ h, float* __restrict__ ro) {
  int bid = blockIdx.x;
  int b = bid / 68;
  int p = (bid % 68) * 4 + (threadIdx.x >> 6);   // 0..271
  int lane = threadIdx.x & 63;
  const float* wrow = Wr + p * Hh;
  const float* hb = h + b * Hh;
  float acc = 0.f;
  #pragma unroll
  for (int t = 0; t < 8; ++t) { int k = lane + 64*t; acc += wrow[k] * hb[k]; }
  acc = wave_reduce(acc);
  if (lane == 0) ro[b*272 + p] = acc + br[p];
}

// ---- 2. rbeta, rpi(softmax3), key_norm ; wave per (b,r) ----
__global__ void k_read_xform(const float* __restrict__ ro, float* __restrict__ rbeta,
                             float* __restrict__ rpi, float* __restrict__ keynorm) {
  int b = blockIdx.x;
  int r = threadIdx.x >> 6, lane = threadIdx.x & 63;
  const float* rob = ro + b*272 + r*ROo;
  float kv = rob[lane];
  float ssq = wave_reduce(kv*kv);
  if (lane == 0) {
    keynorm[b*Rr + r] = fmaxf(sqrtf(ssq), EPSf);
    rbeta[b*Rr + r] = softplusf(rob[64]);
    float e0 = rob[65], e1 = rob[66], e2 = rob[67];
    float m = fmaxf(e0, fmaxf(e1, e2));
    float x0 = expf(e0-m), x1 = expf(e1-m), x2 = expf(e2-m);
    float s = x0+x1+x2;
    rpi[(b*Rr+r)*3+0] = x0/s;
    rpi[(b*Rr+r)*3+1] = x1/s;
    rpi[(b*Rr+r)*3+2] = x2/s;
  }
}

// ---- 3. mem_norm[b,n] ; wave per row ----
__global__ void k_memnorm(const float* __restrict__ mem, float* __restrict__ memnorm) {
  int row = blockIdx.x * 4 + (threadIdx.x >> 6);
  int lane = threadIdx.x & 63;
  float m = mem[row*Vv + lane];
  float ssq = wave_reduce(m*m);
  if (lane == 0) memnorm[row] = fmaxf(sqrtf(ssq), EPSf);
}

// ---- 4. scores[b,r,n] = rbeta * cos-sim ; wave per (b,n), loop r ----
__global__ void k_scores(const float* __restrict__ mem, const float* __restrict__ ro,
                         const float* __restrict__ rbeta, const float* __restrict__ keynorm,
                         const float* __restrict__ memnorm, float* __restrict__ scores) {
  int row = blockIdx.x*4 + (threadIdx.x>>6);
  int lane = threadIdx.x & 63;
  int b = row >> 9, n = row & 511;
  float m = mem[row*Vv + lane];
  float mn = memnorm[row];
  #pragma unroll
  for (int r = 0; r < Rr; ++r) {
    float p = m * ro[b*272 + r*ROo + lane];
    float s = wave_reduce(p);
    if (lane == 0)
      scores[(b*Rr + r)*Nn + n] = rbeta[b*Rr+r] * s / (mn * keynorm[b*Rr+r]);
  }
}

// ---- 5. exact kth-largest (bitonic desc) + masked softmax -> cw ; block per (b,r) ----
__global__ void k_topk_cw(const float* __restrict__ scores, float* __restrict__ cw) {
  __shared__ float sv[512];
  __shared__ float so[512];
  __shared__ float red[256];
  int br = blockIdx.x;
  int tid = threadIdx.x;
  const float* srow = scores + br*Nn;
  for (int i = tid; i < 512; i += 256) { float v = srow[i]; sv[i]=v; so[i]=v; }
  __syncthreads();
  for (int k = 2; k <= 512; k <<= 1) {
    for (int j = k>>1; j > 0; j >>= 1) {
      for (int i = tid; i < 512; i += 256) {
        int ixj = i ^ j;
        if (ixj > i) {
          float a = sv[i], c = sv[ixj];
          bool descSeg = ((i & k) == 0);
          bool sw = descSeg ? (a < c) : (a > c);
          if (sw) { sv[i]=c; sv[ixj]=a; }
        }
      }
      __syncthreads();
    }
  }
  float kth = sv[KTOP-1];
  float mx = sv[0];
  float lsum = 0.f;
  for (int i = tid; i < 512; i += 256) {
    float v = so[i];
    lsum += (v >= kth) ? expf(v - mx) : 0.f;
  }
  red[tid] = lsum; __syncthreads();
  for (int s2 = 128; s2 > 0; s2 >>= 1) {
    if (tid < s2) red[tid] += red[tid+s2];
    __syncthreads();
  }
  float inv = 1.f / red[0];
  for (int i = tid; i < 512; i += 256) {
    float v = so[i];
    cw[br*Nn + i] = (v >= kth) ? expf(v - mx)*inv : 0.f;
  }
}

// ---- 6. fw[b,r,n] = sum_m link[b,n,m]*rw[b,r,m] ; wave per (b,n) ----
__global__ void k_fw(const float* __restrict__ link, const float* __restrict__ rw,
                     float* __restrict__ fw) {
  int row = blockIdx.x*4 + (threadIdx.x>>6);
  int lane = threadIdx.x & 63;
  int b = row >> 9, n = row & 511;
  const float* lrow = link + (size_t)row * Nn;
  const float* rwb = rw + b*Rr*Nn;
  float a0=0,a1=0,a2=0,a3=0;
  #pragma unroll
  for (int t = 0; t < 8; ++t) {
    int k = lane + 64*t;
    float lv = lrow[k];
    a0 += lv * rwb[k];
    a1 += lv * rwb[Nn + k];
    a2 += lv * rwb[2*Nn + k];
    a3 += lv * rwb[3*Nn + k];
  }
  a0 = wave_reduce(a0); a1 = wave_reduce(a1);
  a2 = wave_reduce(a2); a3 = wave_reduce(a3);
  if (lane == 0) {
    fw[(b*Rr+0)*Nn+n] = a0;
    fw[(b*Rr+1)*Nn+n] = a1;
    fw[(b*Rr+2)*Nn+n] = a2;
    fw[(b*Rr+3)*Nn+n] = a3;
  }
}

// ---- 7. bw[b,r,n] = sum_m link[b,m,n]*rw[b,r,m] ; column accumulation ----
__global__ void k_bw(const float* __restrict__ link, const float* __restrict__ rw,
                     float* __restrict__ bw) {
  __shared__ float lds[256*4];
  int b = blockIdx.x >> 2;
  int jt = blockIdx.x & 3;
  int tid = threadIdx.x;
  int j = jt*128 + (tid & 127);
  int half = tid >> 7;
  const float* lb = link + (size_t)b*Nn*Nn;
  const float* rwb = rw + b*Rr*Nn;
  float a0=0,a1=0,a2=0,a3=0;
  int m0 = half*256;
  for (int m = m0; m < m0+256; ++m) {
    float lv = lb[m*Nn + j];
    a0 += lv*rwb[m]; a1 += lv*rwb[Nn+m]; a2 += lv*rwb[2*Nn+m]; a3 += lv*rwb[3*Nn+m];
  }
  lds[tid*4+0]=a0; lds[tid*4+1]=a1; lds[tid*4+2]=a2; lds[tid*4+3]=a3;
  __syncthreads();
  if (tid < 128) {
    int jj = jt*128 + tid;
    #pragma unroll
    for (int r = 0; r < 4; ++r)
      bw[(b*Rr+r)*Nn + jj] = lds[tid*4+r] + lds[(tid+128)*4+r];
  }
}

// ---- 8. w_r, psi, usage_new ; thread per (b,n) ----
__global__ void k_wr_usage(const float* __restrict__ bw, const float* __restrict__ cw,
                           const float* __restrict__ fw, const float* __restrict__ rpi,
                           const float* __restrict__ usage, const float* __restrict__ wwt,
                           float* __restrict__ out_wr, float* __restrict__ out_usage) {
  int idx = blockIdx.x*256 + threadIdx.x;
  int b = idx >> 9, n = idx & 511;
  float psi = 1.f;
  #pragma unroll
  for (int r = 0; r < Rr; ++r) {
    int br = b*Rr + r;
    float p0 = rpi[br*3], p1 = rpi[br*3+1], p2 = rpi[br*3+2];
    float w = p0*bw[br*Nn+n] + p1*cw[br*Nn+n] + p2*fw[br*Nn+n];
    out_wr[br*Nn+n] = w;
    psi *= (1.f - w);
  }
  float u = usage[idx], wt = wwt[idx];
  out_usage[idx] = (u + wt - u*wt) * psi;
}

// ---- 9. rvec[b,r,v] = sum_n w_r[b,r,n]*mem[b,n,v] ; block per b ----
__global__ void k_rvec(const float* __restrict__ wr, const float* __restrict__ mem,
                       float* __restrict__ rvec) {
  int b = blockIdx.x;
  int r = threadIdx.x >> 6, v = threadIdx.x & 63;
  const float* wrow = wr + (b*Rr + r)*Nn;
  const float* mb = mem + (size_t)b*Nn*Vv;
  float acc = 0.f;
  for (int n = 0; n < Nn; ++n)
    acc += wrow[n] * mb[n*Vv + v];
  rvec[(b*Rr+r)*Vv + v] = acc;
}

// ---- 10. gates GEMM ; wave per (j,b), b fastest for W-row temporal reuse ----
__global__ void k_gates(const float* __restrict__ x, const float* __restrict__ rvec,
                        const float* __restrict__ h, const float* __restrict__ Wih,
                        const float* __restrict__ Whh, const float* __restrict__ bih,
                        const float* __restrict__ bhh, float* __restrict__ gates) {
  int gid = blockIdx.x*4 + (threadIdx.x>>6);   // j*64 + b
  int lane = threadIdx.x & 63;
  int j = gid >> 6, b = gid & 63;
  const float* wi = Wih + j*CIN;
  const float* wh = Whh + j*Hh;
  float acc = 0.f;
  #pragma unroll
  for (int t = 0; t < 6; ++t) {
    int k = lane + 64*t;
    float xin = (k < INp) ? x[b*INp + k] : rvec[b*(Rr*Vv) + k - INp];
    acc += xin * wi[k];
  }
  #pragma unroll
  for (int t = 0; t < 8; ++t) {
    int k = lane + 64*t;
    acc += h[b*Hh+k] * wh[k];
  }
  acc = wave_reduce(acc);
  if (lane == 0) gates[b*(4*Hh) + j] = acc + bih[j] + bhh[j];
}

// ---- 11. LSTM elementwise ----
__global__ void k_lstm(const float* __restrict__ gates, const float* __restrict__ c,
                       float* __restrict__ out_h, float* __restrict__ out_c) {
  int idx = blockIdx.x*256 + threadIdx.x;
  int b = idx >> 9, hh = idx & 511;
  const float* g = gates + b*2048;
  float ig = sigmoidf(g[hh]), fg = sigmoidf(g[512+hh]);
  float gg = tanhf(g[1024+hh]), og = sigmoidf(g[1536+hh]);
  float cn = fg * c[idx] + ig * gg;
  float hn = og * tanhf(cn);
  out_c[idx] = cn; out_h[idx] = hn;
}

// ---- 12. wo = h_new @ W_write.T + b_write ; wave per (b,o) ----
__global__ void k_wo(const float* __restrict__ hn, const float* __restrict__ Ww,
                     const float* __restrict__ bw_, float* __restrict__ wo) {
  int gid = blockIdx.x*4 + (threadIdx.x>>6);
  int lane = threadIdx.x & 63;
  int b = gid / WOUT, o = gid % WOUT;
  const float* wrow = Ww + o*Hh;
  const float* hb = hn + b*Hh;
  float acc = 0.f;
  #pragma unroll
  for (int t = 0; t < 8; ++t) { int k = lane+64*t; acc += hb[k]*wrow[k]; }
  acc = wave_reduce(acc);
  if (lane==0) wo[b*WOUT+o] = acc + bw_[o];
}

// ---- 13. wkey_norm ----
__global__ void k_wknorm(const float* __restrict__ wo, float* __restrict__ wkn) {
  int b = blockIdx.x; int lane = threadIdx.x;
  float v = wo[b*WOUT + lane];
  float ssq = wave_reduce(v*v);
  if (lane==0) wkn[b] = fmaxf(sqrtf(ssq), EPSf);
}

// ---- 14. write content weights: wsim -> softmax ; block per b ----
__global__ void k_wcontent(const float* __restrict__ mem, const float* __restrict__ wo,
                           const float* __restrict__ memnorm, const float* __restrict__ wkn,
                           float* __restrict__ cww) {
  __shared__ float s[512];
  __shared__ float red[256];
  int b = blockIdx.x;
  int w = threadIdx.x >> 6, lane = threadIdx.x & 63;
  const float* wob = wo + b*WOUT;
  float kv = wob[lane];
  float wbeta = softplusf(wob[192]);
  float wk = wkn[b];
  const float* mb = mem + (size_t)b*Nn*Vv;
  for (int i = 0; i < 128; ++i) {
    int n = w*128 + i;
    float p = mb[n*Vv + lane] * kv;
    float sm = wave_reduce(p);
    if (lane == 0) s[n] = wbeta * sm / (memnorm[b*Nn+n] * wk);
  }
  __syncthreads();
  int tid = threadIdx.x;
  red[tid] = fmaxf(s[tid], s[tid+256]); __syncthreads();
  for (int s2=128; s2>0; s2>>=1){ if (tid<s2) red[tid] = fmaxf(red[tid],red[tid+s2]); __syncthreads(); }
  float mx = red[0]; __syncthreads();
  float e0 = expf(s[tid]-mx), e1 = expf(s[tid+256]-mx);
  red[tid] = e0+e1; __syncthreads();
  for (int s2=128; s2>0; s2>>=1){ if (tid<s2) red[tid] += red[tid+s2]; __syncthreads(); }
  float inv = 1.f/red[0];
  cww[b*Nn + tid] = e0*inv;
  cww[b*Nn + tid + 256] = e1*inv;
}

// ---- 15. allocation sort + write_w + prec_new ; block per b ----
__global__ void k_alloc(const float* __restrict__ usage, const float* __restrict__ wo,
                        const float* __restrict__ cww, const float* __restrict__ prec,
                        float* __restrict__ out_ww, float* __restrict__ out_prec) {
  __shared__ float uv[512];
  __shared__ int   ui[512];
  __shared__ float cp[512];
  __shared__ float al[512];
  __shared__ float red[256];
  int b = blockIdx.x, tid = threadIdx.x;
  for (int i = tid; i < 512; i += 256) { uv[i] = usage[b*Nn+i]; ui[i] = i; }
  __syncthreads();
  // bitonic ascending by (val, idx) — matches stable argsort
  for (int k = 2; k <= 512; k <<= 1) {
    for (int j = k>>1; j > 0; j >>= 1) {
      for (int i = tid; i < 512; i += 256) {
        int ixj = i ^ j;
        if (ixj > i) {
          float av = uv[i], bv = uv[ixj];
          int ai = ui[i], bi = ui[ixj];
          bool gt = (av > bv) || (av == bv && ai > bi);
          bool asc = ((i & k) == 0);
          bool sw = asc ? gt : !gt;
          if (sw) { uv[i]=bv; uv[ixj]=av; ui[i]=bi; ui[ixj]=ai; }
        }
      }
      __syncthreads();
    }
  }
  for (int i = tid; i < 512; i += 256) cp[i] = uv[i];
  __syncthreads();
  // inclusive cumprod (Hillis-Steele)
  for (int d = 1; d < 512; d <<= 1) {
    float t0 = cp[tid]     * ((tid >= d)     ? cp[tid-d]     : 1.f);
    float t1 = cp[tid+256] * ((tid+256 >= d) ? cp[tid+256-d] : 1.f);
    __syncthreads();
    cp[tid] = t0; cp[tid+256] = t1;
    __syncthreads();
  }
  for (int i = tid; i < 512; i += 256) {
    float pp = (i == 0) ? 1.f : cp[i-1];
    al[ui[i]] = (1.f - uv[i]) * pp;
  }
  __syncthreads();
  float ga = sigmoidf(wo[b*WOUT+193]);
  float gw = sigmoidf(wo[b*WOUT+194]);
  float wv0, wv1, lsum;
  {
    int n0 = tid, n1 = tid+256;
    wv0 = gw * (ga*al[n0] + (1.f-ga)*cww[b*Nn+n0]);
    wv1 = gw * (ga*al[n1] + (1.f-ga)*cww[b*Nn+n1]);
    out_ww[b*Nn+n0] = wv0; out_ww[b*Nn+n1] = wv1;
    lsum = wv0 + wv1;
  }
  red[tid] = lsum; __syncthreads();
  for (int s2=128; s2>0; s2>>=1){ if (tid<s2) red[tid]+=red[tid+s2]; __syncthreads(); }
  float wsum = red[0];
  out_prec[b*Nn+tid]     = (1.f - wsum)*prec[b*Nn+tid]     + wv0;
  out_prec[b*Nn+tid+256] = (1.f - wsum)*prec[b*Nn+tid+256] + wv1;
}

// ---- 16. mem_new elementwise, float4 ----
__global__ void k_memnew(const float* __restrict__ mem, const float* __restrict__ wo,
                         const float* __restrict__ ww, float* __restrict__ out_mem) {
  int idx4 = blockIdx.x*256 + threadIdx.x;
  int base = idx4*4;
  int b = base >> 15;
  int rem = base & 32767;
  int n = rem >> 6;
  int v0 = rem & 63;
  float w = ww[b*Nn + n];
  const float* wob = wo + b*WOUT;
  float4 m = *(const float4*)(mem + base);
  float4 o;
  float e, a;
  e = sigmoidf(wob[64+v0+0]); a = tanhf(wob[128+v0+0]); o.x = m.x*(1.f-w*e)+w*a;
  e = sigmoidf(wob[64+v0+1]); a = tanhf(wob[128+v0+1]); o.y = m.y*(1.f-w*e)+w*a;
  e = sigmoidf(wob[64+v0+2]); a = tanhf(wob[128+v0+2]); o.z = m.z*(1.f-w*e)+w*a;
  e = sigmoidf(wob[64+v0+3]); a = tanhf(wob[128+v0+3]); o.w = m.w*(1.f-w*e)+w*a;
  *(float4*)(out_mem + base) = o;
}

// ---- 17. link_new elementwise, float4, zero diagonal ----
__global__ void k_link(const float* __restrict__ link, const float* __restrict__ ww,
                       const float* __restrict__ prec, float* __restrict__ out_link) {
  int idx4 = blockIdx.x*256 + threadIdx.x;
  int base = idx4*4;
  int b = base >> 18;
  int rem = base & 262143;
  int i = rem >> 9;
  int j0 = rem & 511;
  float wi = ww[b*Nn + i];
  float fi = 1.f - wi;
  float4 lv = *(const float4*)(link + base);
  float4 wj = *(const float4*)(ww + b*Nn + j0);
  float4 pj = *(const float4*)(prec + b*Nn + j0);
  float4 o;
  o.x = fi*(1.f-wj.x)*lv.x + wi*pj.x;
  o.y = fi*(1.f-wj.y)*lv.y + wi*pj.y;
  o.z = fi*(1.f-wj.z)*lv.z + wi*pj.z;
  o.w = fi*(1.f-wj.w)*lv.w + wi*pj.w;
  if (i >= j0 && i < j0+4) {
    if (i == j0) o.x = 0.f;
    else if (i == j0+1) o.y = 0.f;
    else if (i == j0+2) o.z = 0.f;
    else o.w = 0.f;
  }
  *(float4*)(out_link + base) = o;
}

// ---- 18. policy logits + value ; wave per (b, o in [0,19)) ----
__global__ void k_polval(const float* __restrict__ hn, const float* __restrict__ Wp,
                         const float* __restrict__ bp, const float* __restrict__ Wv,
                         const float* __restrict__ bv, float* __restrict__ out_logits,
                         float* __restrict__ out_value) {
  int gid = blockIdx.x*4 + (threadIdx.x>>6);
  int lane = threadIdx.x & 63;
  int b = gid / 19, o = gid % 19;
  const float* hb = hn + b*Hh;
  const float* wrow = (o < Aa) ? (Wp + o*Hh) : Wv;
  float acc = 0.f;
  #pragma unroll
  for (int t = 0; t < 8; ++t) { int k = lane+64*t; acc += hb[k]*wrow[k]; }
  acc = wave_reduce(acc);
  if (lane == 0) {
    if (o < Aa) out_logits[b*Aa+o] = acc + bp[o];
    else out_value[b] = acc + bv[0];
  }
}

extern "C" void kernel_launch(void* const* d_in, const int* in_sizes, int n_in,
                              void* d_out, int out_size, void* d_ws, size_t ws_size,
                              hipStream_t stream) {
  const float* x    = (const float*)d_in[0];
  const float* h    = (const float*)d_in[1];
  const float* c    = (const float*)d_in[2];
  const float* mem  = (const float*)d_in[3];
  const float* rw   = (const float*)d_in[4];
  const float* wwt  = (const float*)d_in[5];
  const float* usage= (const float*)d_in[6];
  const float* link = (const float*)d_in[7];
  const float* prec = (const float*)d_in[8];
  const float* Wih  = (const float*)d_in[9];
  const float* Whh  = (const float*)d_in[10];
  const float* bih  = (const float*)d_in[11];
  const float* bhh  = (const float*)d_in[12];
  const float* Wr   = (const float*)d_in[13];
  const float* br   = (const float*)d_in[14];
  const float* Ww   = (const float*)d_in[15];
  const float* bw_  = (const float*)d_in[16];
  const float* Wp   = (const float*)d_in[17];
  const float* bp   = (const float*)d_in[18];
  const float* Wv   = (const float*)d_in[19];
  const float* bv   = (const float*)d_in[20];

  float* out = (float*)d_out;
  float* o_logits = out + 0;
  float* o_value  = out + 1152;
  float* o_h      = out + 1216;
  float* o_c      = out + 33984;
  float* o_mem    = out + 66752;
  float* o_wr     = out + 2163904;
  float* o_ww     = out + 2294976;
  float* o_usage  = out + 2327744;
  float* o_link   = out + 2360512;
  float* o_prec   = out + 19137728;

  float* ws = (float*)d_ws;
  float* ws_ro     = ws;            // 17408
  float* ws_rbeta  = ws + 17408;    // 256
  float* ws_rpi    = ws + 17664;    // 768
  float* ws_kn     = ws + 18432;    // 256
  float* ws_mn     = ws + 18688;    // 32768
  float* ws_sc     = ws + 51456;    // 131072
  float* ws_cw     = ws + 182528;   // 131072
  float* ws_fw     = ws + 313600;   // 131072
  float* ws_bw     = ws + 444672;   // 131072
  float* ws_rvec   = ws + 575744;   // 16384
  float* ws_gates  = ws + 592128;   // 131072
  float* ws_wo     = ws + 723200;   // 12480
  float* ws_wkn    = ws + 735680;   // 64
  float* ws_cww    = ws + 735744;   // 32768 (end: 768512 floats ≈ 3.0 MB)

  k_read_proj <<<dim3(Bb*68),      dim3(256), 0, stream>>>(Wr, br, h, ws_ro);
  k_read_xform<<<dim3(Bb),         dim3(256), 0, stream>>>(ws_ro, ws_rbeta, ws_rpi, ws_kn);
  k_memnorm   <<<dim3(Bb*Nn/4),    dim3(256), 0, stream>>>(mem, ws_mn);
  k_scores    <<<dim3(Bb*Nn/4),    dim3(256), 0, stream>>>(mem, ws_ro, ws_rbeta, ws_kn, ws_mn, ws_sc);
  k_topk_cw   <<<dim3(Bb*Rr),      dim3(256), 0, stream>>>(ws_sc, ws_cw);
  k_fw        <<<dim3(Bb*Nn/4),    dim3(256), 0, stream>>>(link, rw, ws_fw);
  k_bw        <<<dim3(Bb*4),       dim3(256), 0, stream>>>(link, rw, ws_bw);
  k_wr_usage  <<<dim3(Bb*Nn/256),  dim3(256), 0, stream>>>(ws_bw, ws_cw, ws_fw, ws_rpi, usage, wwt, o_wr, o_usage);
  k_rvec      <<<dim3(Bb),         dim3(256), 0, stream>>>(o_wr, mem, ws_rvec);
  k_gates     <<<dim3(2048*Bb/4),  dim3(256), 0, stream>>>(x, ws_rvec, h, Wih, Whh, bih, bhh, ws_gates);
  k_lstm      <<<dim3(Bb*Hh/256),  dim3(256), 0, stream>>>(ws_gates, c, o_h, o_c);
  k_wo        <<<dim3(Bb*WOUT/4),  dim3(256), 0, stream>>>(o_h, Ww, bw_, ws_wo);
  k_wknorm    <<<dim3(Bb),         dim3(64),  0, stream>>>(ws_wo, ws_wkn);
  k_wcontent  <<<dim3(Bb),         dim3(256), 0, stream>>>(mem, ws_wo, ws_mn, ws_wkn, ws_cww);
  k_alloc     <<<dim3(Bb),         dim3(256), 0, stream>>>(usage, ws_wo, ws_cww, prec, o_ww, o_prec);
  k_memnew    <<<dim3(Bb*Nn*Vv/1024), dim3(256), 0, stream>>>(mem, ws_wo, o_ww, o_mem);
  k_link      <<<dim3(Bb*Nn*Nn/1024), dim3(256), 0, stream>>>(link, o_ww, prec, o_link);
  k_polval    <<<dim3(Bb*19/4),    dim3(256), 0, stream>>>(o_h, Wp, bp, Wv, bv, o_logits, o_value);
}

// Round 2
// 356.364 us; speedup vs baseline: 1.3191x; 1.3191x over previous
//
#include <hip/hip_runtime.h>
#include <math.h>

constexpr int Bb = 64, Nn = 512, Vv = 64, Hh = 512, Rr = 4, Aa = 18, INp = 128, KTOP = 32;
constexpr int CIN = 384;   // IN + R*V
constexpr int ROo = 68;    // V+4
constexpr int WOUT = 195;  // 3V+3
#define EPSf 1e-8f

__device__ __forceinline__ float sigmoidf(float x){ return 1.f/(1.f+expf(-x)); }
__device__ __forceinline__ float softplusf(float x){ return (x>20.f)? x : log1pf(expf(x)); }
__device__ __forceinline__ float wave_reduce(float v){
  #pragma unroll
  for(int o=32;o>0;o>>=1) v += __shfl_down(v, o, 64);
  return v;
}

// ---- 1. ro = W_read @ h + b_read ; one wave per (b, r*68+o) output ----
__global__ void k_read_proj(const float* __restrict__ Wr, const float* __restrict__ br,
                            const float* __restrict__ h, float* __restrict__ ro) {
  int bid = blockIdx.x;
  int b = bid / 68;
  int p = (bid % 68) * 4 + (threadIdx.x >> 6);   // 0..271
  int lane = threadIdx.x & 63;
  const float* wrow = Wr + p * Hh;
  const float* hb = h + b * Hh;
  float acc = 0.f;
  #pragma unroll
  for (int t = 0; t < 8; ++t) { int k = lane + 64*t; acc += wrow[k] * hb[k]; }
  acc = wave_reduce(acc);
  if (lane == 0) ro[b*272 + p] = acc + br[p];
}

// ---- 2. rbeta, rpi(softmax3), key_norm ; wave per (b,r) ----
__global__ void k_read_xform(const float* __restrict__ ro, float* __restrict__ rbeta,
                             float* __restrict__ rpi, float* __restrict__ keynorm) {
  int b = blockIdx.x;
  int r = threadIdx.x >> 6, lane = threadIdx.x & 63;
  const float* rob = ro + b*272 + r*ROo;
  float kv = rob[lane];
  float ssq = wave_reduce(kv*kv);
  if (lane == 0) {
    keynorm[b*Rr + r] = fmaxf(sqrtf(ssq), EPSf);
    rbeta[b*Rr + r] = softplusf(rob[64]);
    float e0 = rob[65], e1 = rob[66], e2 = rob[67];
    float m = fmaxf(e0, fmaxf(e1, e2));
    float x0 = expf(e0-m), x1 = expf(e1-m), x2 = expf(e2-m);
    float s = x0+x1+x2;
    rpi[(b*Rr+r)*3+0] = x0/s;
    rpi[(b*Rr+r)*3+1] = x1/s;
    rpi[(b*Rr+r)*3+2] = x2/s;
  }
}

// ---- 3. mem_norm[b,n] ; wave per row ----
__global__ void k_memnorm(const float* __restrict__ mem, float* __restrict__ memnorm) {
  int row = blockIdx.x * 4 + (threadIdx.x >> 6);
  int lane = threadIdx.x & 63;
  float m = mem[row*Vv + lane];
  float ssq = wave_reduce(m*m);
  if (lane == 0) memnorm[row] = fmaxf(sqrtf(ssq), EPSf);
}

// ---- 4. scores[b,r,n] = rbeta * cos-sim ; wave per (b,n), loop r ----
__global__ void k_scores(const float* __restrict__ mem, const float* __restrict__ ro,
                         const float* __restrict__ rbeta, const float* __restrict__ keynorm,
                         const float* __restrict__ memnorm, float* __restrict__ scores) {
  int row = blockIdx.x*4 + (threadIdx.x>>6);
  int lane = threadIdx.x & 63;
  int b = row >> 9, n = row & 511;
  float m = mem[row*Vv + lane];
  float mn = memnorm[row];
  #pragma unroll
  for (int r = 0; r < Rr; ++r) {
    float p = m * ro[b*272 + r*ROo + lane];
    float s = wave_reduce(p);
    if (lane == 0)
      scores[(b*Rr + r)*Nn + n] = rbeta[b*Rr+r] * s / (mn * keynorm[b*Rr+r]);
  }
}

// ---- 5. exact kth-largest (bitonic desc) + masked softmax -> cw ; block per (b,r) ----
__global__ void k_topk_cw(const float* __restrict__ scores, float* __restrict__ cw) {
  __shared__ float sv[512];
  __shared__ float so[512];
  __shared__ float red[256];
  int br = blockIdx.x;
  int tid = threadIdx.x;
  const float* srow = scores + br*Nn;
  for (int i = tid; i < 512; i += 256) { float v = srow[i]; sv[i]=v; so[i]=v; }
  __syncthreads();
  for (int k = 2; k <= 512; k <<= 1) {
    for (int j = k>>1; j > 0; j >>= 1) {
      for (int i = tid; i < 512; i += 256) {
        int ixj = i ^ j;
        if (ixj > i) {
          float a = sv[i], c = sv[ixj];
          bool descSeg = ((i & k) == 0);
          bool sw = descSeg ? (a < c) : (a > c);
          if (sw) { sv[i]=c; sv[ixj]=a; }
        }
      }
      __syncthreads();
    }
  }
  float kth = sv[KTOP-1];
  float mx = sv[0];
  float lsum = 0.f;
  for (int i = tid; i < 512; i += 256) {
    float v = so[i];
    lsum += (v >= kth) ? expf(v - mx) : 0.f;
  }
  red[tid] = lsum; __syncthreads();
  for (int s2 = 128; s2 > 0; s2 >>= 1) {
    if (tid < s2) red[tid] += red[tid+s2];
    __syncthreads();
  }
  float inv = 1.f / red[0];
  for (int i = tid; i < 512; i += 256) {
    float v = so[i];
    cw[br*Nn + i] = (v >= kth) ? expf(v - mx)*inv : 0.f;
  }
}

// ---- 6. fw[b,r,n] = sum_m link[b,n,m]*rw[b,r,m] ; wave per (b,n) ----
__global__ void k_fw(const float* __restrict__ link, const float* __restrict__ rw,
                     float* __restrict__ fw) {
  int row = blockIdx.x*4 + (threadIdx.x>>6);
  int lane = threadIdx.x & 63;
  int b = row >> 9, n = row & 511;
  const float* lrow = link + (size_t)row * Nn;
  const float* rwb = rw + b*Rr*Nn;
  float a0=0,a1=0,a2=0,a3=0;
  #pragma unroll
  for (int t = 0; t < 8; ++t) {
    int k = lane + 64*t;
    float lv = lrow[k];
    a0 += lv * rwb[k];
    a1 += lv * rwb[Nn + k];
    a2 += lv * rwb[2*Nn + k];
    a3 += lv * rwb[3*Nn + k];
  }
  a0 = wave_reduce(a0); a1 = wave_reduce(a1);
  a2 = wave_reduce(a2); a3 = wave_reduce(a3);
  if (lane == 0) {
    fw[(b*Rr+0)*Nn+n] = a0;
    fw[(b*Rr+1)*Nn+n] = a1;
    fw[(b*Rr+2)*Nn+n] = a2;
    fw[(b*Rr+3)*Nn+n] = a3;
  }
}

// ---- 7. bw[b,r,n] = sum_m link[b,m,n]*rw[b,r,m] ; (b, j-tile, m-chunk) blocks, atomic ----
__global__ void k_bw(const float* __restrict__ link, const float* __restrict__ rw,
                     float* __restrict__ bw) {
  __shared__ float lds[256*4];
  int b  = blockIdx.x >> 4;
  int jt = (blockIdx.x >> 2) & 3;
  int mc = blockIdx.x & 3;
  int tid = threadIdx.x;
  int j = jt*128 + (tid & 127);
  int half = tid >> 7;
  const float* lb = link + (size_t)b*Nn*Nn;
  const float* rwb = rw + b*Rr*Nn;
  float a0=0,a1=0,a2=0,a3=0;
  int m0 = mc*128 + half*64;
  for (int m = m0; m < m0+64; ++m) {
    float lv = lb[m*Nn + j];
    a0 += lv*rwb[m]; a1 += lv*rwb[Nn+m]; a2 += lv*rwb[2*Nn+m]; a3 += lv*rwb[3*Nn+m];
  }
  lds[tid*4+0]=a0; lds[tid*4+1]=a1; lds[tid*4+2]=a2; lds[tid*4+3]=a3;
  __syncthreads();
  if (tid < 128) {
    int jj = jt*128 + tid;
    #pragma unroll
    for (int r = 0; r < 4; ++r)
      atomicAdd(&bw[(b*Rr+r)*Nn + jj], lds[tid*4+r] + lds[(tid+128)*4+r]);
  }
}

// ---- 8. w_r, psi, usage_new ; thread per (b,n) ----
__global__ void k_wr_usage(const float* __restrict__ bw, const float* __restrict__ cw,
                           const float* __restrict__ fw, const float* __restrict__ rpi,
                           const float* __restrict__ usage, const float* __restrict__ wwt,
                           float* __restrict__ out_wr, float* __restrict__ out_usage) {
  int idx = blockIdx.x*256 + threadIdx.x;
  int b = idx >> 9, n = idx & 511;
  float psi = 1.f;
  #pragma unroll
  for (int r = 0; r < Rr; ++r) {
    int br = b*Rr + r;
    float p0 = rpi[br*3], p1 = rpi[br*3+1], p2 = rpi[br*3+2];
    float w = p0*bw[br*Nn+n] + p1*cw[br*Nn+n] + p2*fw[br*Nn+n];
    out_wr[br*Nn+n] = w;
    psi *= (1.f - w);
  }
  float u = usage[idx], wt = wwt[idx];
  out_usage[idx] = (u + wt - u*wt) * psi;
}

// ---- 9. rvec[b,r,v] = sum_n w_r[b,r,n]*mem[b,n,v] ; (b, n-chunk) blocks, atomic ----
__global__ void k_rvec(const float* __restrict__ wr, const float* __restrict__ mem,
                       float* __restrict__ rvec) {
  int b = blockIdx.x >> 3;
  int ch = blockIdx.x & 7;
  int r = threadIdx.x >> 6, v = threadIdx.x & 63;
  const float* wrow = wr + (b*Rr + r)*Nn;
  const float* mb = mem + (size_t)b*Nn*Vv;
  float acc = 0.f;
  #pragma unroll 4
  for (int t = 0; t < 64; ++t) {
    int n = ch*64 + t;
    acc += wrow[n] * mb[n*Vv + v];
  }
  atomicAdd(&rvec[(b*Rr+r)*Vv + v], acc);
}

// ---- 10. gates GEMM ; wave per (j,b), b fastest for W-row temporal reuse ----
__global__ void k_gates(const float* __restrict__ x, const float* __restrict__ rvec,
                        const float* __restrict__ h, const float* __restrict__ Wih,
                        const float* __restrict__ Whh, const float* __restrict__ bih,
                        const float* __restrict__ bhh, float* __restrict__ gates) {
  int gid = blockIdx.x*4 + (threadIdx.x>>6);   // j*64 + b
  int lane = threadIdx.x & 63;
  int j = gid >> 6, b = gid & 63;
  const float* wi = Wih + j*CIN;
  const float* wh = Whh + j*Hh;
  float acc = 0.f;
  #pragma unroll
  for (int t = 0; t < 6; ++t) {
    int k = lane + 64*t;
    float xin = (k < INp) ? x[b*INp + k] : rvec[b*(Rr*Vv) + k - INp];
    acc += xin * wi[k];
  }
  #pragma unroll
  for (int t = 0; t < 8; ++t) {
    int k = lane + 64*t;
    acc += h[b*Hh+k] * wh[k];
  }
  acc = wave_reduce(acc);
  if (lane == 0) gates[b*(4*Hh) + j] = acc + bih[j] + bhh[j];
}

// ---- 11. LSTM elementwise ----
__global__ void k_lstm(const float* __restrict__ gates, const float* __restrict__ c,
                       float* __restrict__ out_h, float* __restrict__ out_c) {
  int idx = blockIdx.x*256 + threadIdx.x;
  int b = idx >> 9, hh = idx & 511;
  const float* g = gates + b*2048;
  float ig = sigmoidf(g[hh]), fg = sigmoidf(g[512+hh]);
  float gg = tanhf(g[1024+hh]), og = sigmoidf(g[1536+hh]);
  float cn = fg * c[idx] + ig * gg;
  float hn = og * tanhf(cn);
  out_c[idx] = cn; out_h[idx] = hn;
}

// ---- 12. wo = h_new @ W_write.T + b_write ; wave per (b,o) ----
__global__ void k_wo(const float* __restrict__ hn, const float* __restrict__ Ww,
                     const float* __restrict__ bw_, float* __restrict__ wo) {
  int gid = blockIdx.x*4 + (threadIdx.x>>6);
  int lane = threadIdx.x & 63;
  int b = gid / WOUT, o = gid % WOUT;
  const float* wrow = Ww + o*Hh;
  const float* hb = hn + b*Hh;
  float acc = 0.f;
  #pragma unroll
  for (int t = 0; t < 8; ++t) { int k = lane+64*t; acc += hb[k]*wrow[k]; }
  acc = wave_reduce(acc);
  if (lane==0) wo[b*WOUT+o] = acc + bw_[o];
}

// ---- 13. wkey_norm ----
__global__ void k_wknorm(const float* __restrict__ wo, float* __restrict__ wkn) {
  int b = blockIdx.x; int lane = threadIdx.x;
  float v = wo[b*WOUT + lane];
  float ssq = wave_reduce(v*v);
  if (lane==0) wkn[b] = fmaxf(sqrtf(ssq), EPSf);
}

// ---- 14. wsim scores (scaled) ; wave per (b,n) ----
__global__ void k_wsim(const float* __restrict__ mem, const float* __restrict__ wo,
                       const float* __restrict__ memnorm, const float* __restrict__ wkn,
                       float* __restrict__ wsim) {
  int row = blockIdx.x*4 + (threadIdx.x>>6);
  int lane = threadIdx.x & 63;
  int b = row >> 9, n = row & 511;
  const float* wob = wo + b*WOUT;
  float p = mem[row*Vv + lane] * wob[lane];
  float s = wave_reduce(p);
  if (lane == 0) {
    float wbeta = softplusf(wob[192]);
    wsim[row] = wbeta * s / (memnorm[row] * wkn[b]);
  }
}

// ---- 15. softmax(wsim) + allocation sort + write_w + prec_new ; block per b ----
__global__ void k_alloc(const float* __restrict__ usage, const float* __restrict__ wo,
                        const float* __restrict__ wsim, const float* __restrict__ prec,
                        float* __restrict__ out_ww, float* __restrict__ out_prec) {
  __shared__ float uv[512];
  __shared__ int   ui[512];
  __shared__ float cp[512];
  __shared__ float al[512];
  __shared__ float red[256];
  int b = blockIdx.x, tid = threadIdx.x;
  // --- softmax of wsim -> cww (registers c0,c1) ---
  float s0 = wsim[b*Nn + tid], s1 = wsim[b*Nn + tid + 256];
  red[tid] = fmaxf(s0, s1); __syncthreads();
  for (int s2=128; s2>0; s2>>=1){ if (tid<s2) red[tid]=fmaxf(red[tid],red[tid+s2]); __syncthreads(); }
  float mx = red[0]; __syncthreads();
  float e0 = expf(s0-mx), e1 = expf(s1-mx);
  red[tid] = e0+e1; __syncthreads();
  for (int s2=128; s2>0; s2>>=1){ if (tid<s2) red[tid]+=red[tid+s2]; __syncthreads(); }
  float cinv = 1.f/red[0];
  float c0 = e0*cinv, c1 = e1*cinv;
  __syncthreads();
  // --- bitonic ascending argsort of usage by (val, idx) ---
  for (int i = tid; i < 512; i += 256) { uv[i] = usage[b*Nn+i]; ui[i] = i; }
  __syncthreads();
  for (int k = 2; k <= 512; k <<= 1) {
    for (int j = k>>1; j > 0; j >>= 1) {
      for (int i = tid; i < 512; i += 256) {
        int ixj = i ^ j;
        if (ixj > i) {
          float av = uv[i], bv = uv[ixj];
          int ai = ui[i], bi = ui[ixj];
          bool gt = (av > bv) || (av == bv && ai > bi);
          bool asc = ((i & k) == 0);
          bool sw = asc ? gt : !gt;
          if (sw) { uv[i]=bv; uv[ixj]=av; ui[i]=bi; ui[ixj]=ai; }
        }
      }
      __syncthreads();
    }
  }
  for (int i = tid; i < 512; i += 256) cp[i] = uv[i];
  __syncthreads();
  // inclusive cumprod (Hillis-Steele)
  for (int d = 1; d < 512; d <<= 1) {
    float t0 = cp[tid]     * ((tid >= d)     ? cp[tid-d]     : 1.f);
    float t1 = cp[tid+256] * ((tid+256 >= d) ? cp[tid+256-d] : 1.f);
    __syncthreads();
    cp[tid] = t0; cp[tid+256] = t1;
    __syncthreads();
  }
  for (int i = tid; i < 512; i += 256) {
    float pp = (i == 0) ? 1.f : cp[i-1];
    al[ui[i]] = (1.f - uv[i]) * pp;
  }
  __syncthreads();
  float ga = sigmoidf(wo[b*WOUT+193]);
  float gw = sigmoidf(wo[b*WOUT+194]);
  int n0 = tid, n1 = tid+256;
  float wv0 = gw * (ga*al[n0] + (1.f-ga)*c0);
  float wv1 = gw * (ga*al[n1] + (1.f-ga)*c1);
  out_ww[b*Nn+n0] = wv0; out_ww[b*Nn+n1] = wv1;
  red[tid] = wv0 + wv1; __syncthreads();
  for (int s2=128; s2>0; s2>>=1){ if (tid<s2) red[tid]+=red[tid+s2]; __syncthreads(); }
  float wsum = red[0];
  out_prec[b*Nn+n0] = (1.f - wsum)*prec[b*Nn+n0] + wv0;
  out_prec[b*Nn+n1] = (1.f - wsum)*prec[b*Nn+n1] + wv1;
}

// ---- 16. mem_new elementwise, float4 ----
__global__ void k_memnew(const float* __restrict__ mem, const float* __restrict__ wo,
                         const float* __restrict__ ww, float* __restrict__ out_mem) {
  int idx4 = blockIdx.x*256 + threadIdx.x;
  int base = idx4*4;
  int b = base >> 15;
  int rem = base & 32767;
  int n = rem >> 6;
  int v0 = rem & 63;
  float w = ww[b*Nn + n];
  const float* wob = wo + b*WOUT;
  float4 m = *(const float4*)(mem + base);
  float4 o;
  float e, a;
  e = sigmoidf(wob[64+v0+0]); a = tanhf(wob[128+v0+0]); o.x = m.x*(1.f-w*e)+w*a;
  e = sigmoidf(wob[64+v0+1]); a = tanhf(wob[128+v0+1]); o.y = m.y*(1.f-w*e)+w*a;
  e = sigmoidf(wob[64+v0+2]); a = tanhf(wob[128+v0+2]); o.z = m.z*(1.f-w*e)+w*a;
  e = sigmoidf(wob[64+v0+3]); a = tanhf(wob[128+v0+3]); o.w = m.w*(1.f-w*e)+w*a;
  *(float4*)(out_mem + base) = o;
}

// ---- 17. link_new elementwise, float4, zero diagonal ----
__global__ void k_link(const float* __restrict__ link, const float* __restrict__ ww,
                       const float* __restrict__ prec, float* __restrict__ out_link) {
  int idx4 = blockIdx.x*256 + threadIdx.x;
  int base = idx4*4;
  int b = base >> 18;
  int rem = base & 262143;
  int i = rem >> 9;
  int j0 = rem & 511;
  float wi = ww[b*Nn + i];
  float fi = 1.f - wi;
  float4 lv = *(const float4*)(link + base);
  float4 wj = *(const float4*)(ww + b*Nn + j0);
  float4 pj = *(const float4*)(prec + b*Nn + j0);
  float4 o;
  o.x = fi*(1.f-wj.x)*lv.x + wi*pj.x;
  o.y = fi*(1.f-wj.y)*lv.y + wi*pj.y;
  o.z = fi*(1.f-wj.z)*lv.z + wi*pj.z;
  o.w = fi*(1.f-wj.w)*lv.w + wi*pj.w;
  if (i >= j0 && i < j0+4) {
    if (i == j0) o.x = 0.f;
    else if (i == j0+1) o.y = 0.f;
    else if (i == j0+2) o.z = 0.f;
    else o.w = 0.f;
  }
  *(float4*)(out_link + base) = o;
}

// ---- 18. policy logits + value ; wave per (b, o in [0,19)) ----
__global__ void k_polval(const float* __restrict__ hn, const float* __restrict__ Wp,
                         const float* __restrict__ bp, const float* __restrict__ Wv,
                         const float* __restrict__ bv, float* __restrict__ out_logits,
                         float* __restrict__ out_value) {
  int gid = blockIdx.x*4 + (threadIdx.x>>6);
  int lane = threadIdx.x & 63;
  int b = gid / 19, o = gid % 19;
  const float* hb = hn + b*Hh;
  const float* wrow = (o < Aa) ? (Wp + o*Hh) : Wv;
  float acc = 0.f;
  #pragma unroll
  for (int t = 0; t < 8; ++t) { int k = lane+64*t; acc += hb[k]*wrow[k]; }
  acc = wave_reduce(acc);
  if (lane == 0) {
    if (o < Aa) out_logits[b*Aa+o] = acc + bp[o];
    else out_value[b] = acc + bv[0];
  }
}

extern "C" void kernel_launch(void* const* d_in, const int* in_sizes, int n_in,
                              void* d_out, int out_size, void* d_ws, size_t ws_size,
                              hipStream_t stream) {
  const float* x    = (const float*)d_in[0];
  const float* h    = (const float*)d_in[1];
  const float* c    = (const float*)d_in[2];
  const float* mem  = (const float*)d_in[3];
  const float* rw   = (const float*)d_in[4];
  const float* wwt  = (const float*)d_in[5];
  const float* usage= (const float*)d_in[6];
  const float* link = (const float*)d_in[7];
  const float* prec = (const float*)d_in[8];
  const float* Wih  = (const float*)d_in[9];
  const float* Whh  = (const float*)d_in[10];
  const float* bih  = (const float*)d_in[11];
  const float* bhh  = (const float*)d_in[12];
  const float* Wr   = (const float*)d_in[13];
  const float* br   = (const float*)d_in[14];
  const float* Ww   = (const float*)d_in[15];
  const float* bw_  = (const float*)d_in[16];
  const float* Wp   = (const float*)d_in[17];
  const float* bp   = (const float*)d_in[18];
  const float* Wv   = (const float*)d_in[19];
  const float* bv   = (const float*)d_in[20];

  float* out = (float*)d_out;
  float* o_logits = out + 0;
  float* o_value  = out + 1152;
  float* o_h      = out + 1216;
  float* o_c      = out + 33984;
  float* o_mem    = out + 66752;
  float* o_wr     = out + 2163904;
  float* o_ww     = out + 2294976;
  float* o_usage  = out + 2327744;
  float* o_link   = out + 2360512;
  float* o_prec   = out + 19137728;

  float* ws = (float*)d_ws;
  float* ws_ro     = ws;            // 17408
  float* ws_rbeta  = ws + 17408;    // 256
  float* ws_rpi    = ws + 17664;    // 768
  float* ws_kn     = ws + 18432;    // 256
  float* ws_mn     = ws + 18688;    // 32768
  float* ws_sc     = ws + 51456;    // 131072
  float* ws_cw     = ws + 182528;   // 131072
  float* ws_fw     = ws + 313600;   // 131072
  float* ws_bw     = ws + 444672;   // 131072  (atomic-accumulated, memset)
  float* ws_rvec   = ws + 575744;   // 16384   (atomic-accumulated, memset)
  float* ws_gates  = ws + 592128;   // 131072
  float* ws_wo     = ws + 723200;   // 12480
  float* ws_wkn    = ws + 735680;   // 64
  float* ws_wsim   = ws + 735744;   // 32768

  hipMemsetAsync(ws_bw,   0, 131072*sizeof(float), stream);
  hipMemsetAsync(ws_rvec, 0, 16384*sizeof(float),  stream);

  k_read_proj <<<dim3(Bb*68),      dim3(256), 0, stream>>>(Wr, br, h, ws_ro);
  k_read_xform<<<dim3(Bb),         dim3(256), 0, stream>>>(ws_ro, ws_rbeta, ws_rpi, ws_kn);
  k_memnorm   <<<dim3(Bb*Nn/4),    dim3(256), 0, stream>>>(mem, ws_mn);
  k_scores    <<<dim3(Bb*Nn/4),    dim3(256), 0, stream>>>(mem, ws_ro, ws_rbeta, ws_kn, ws_mn, ws_sc);
  k_topk_cw   <<<dim3(Bb*Rr),      dim3(256), 0, stream>>>(ws_sc, ws_cw);
  k_fw        <<<dim3(Bb*Nn/4),    dim3(256), 0, stream>>>(link, rw, ws_fw);
  k_bw        <<<dim3(Bb*16),      dim3(256), 0, stream>>>(link, rw, ws_bw);
  k_wr_usage  <<<dim3(Bb*Nn/256),  dim3(256), 0, stream>>>(ws_bw, ws_cw, ws_fw, ws_rpi, usage, wwt, o_wr, o_usage);
  k_rvec      <<<dim3(Bb*8),       dim3(256), 0, stream>>>(o_wr, mem, ws_rvec);
  k_gates     <<<dim3(2048*Bb/4),  dim3(256), 0, stream>>>(x, ws_rvec, h, Wih, Whh, bih, bhh, ws_gates);
  k_lstm      <<<dim3(Bb*Hh/256),  dim3(256), 0, stream>>>(ws_gates, c, o_h, o_c);
  k_wo        <<<dim3(Bb*WOUT/4),  dim3(256), 0, stream>>>(o_h, Ww, bw_, ws_wo);
  k_wknorm    <<<dim3(Bb),         dim3(64),  0, stream>>>(ws_wo, ws_wkn);
  k_wsim      <<<dim3(Bb*Nn/4),    dim3(256), 0, stream>>>(mem, ws_wo, ws_mn, ws_wkn, ws_wsim);
  k_alloc     <<<dim3(Bb),         dim3(256), 0, stream>>>(usage, ws_wo, ws_wsim, prec, o_ww, o_prec);
  k_memnew    <<<dim3(Bb*Nn*Vv/1024), dim3(256), 0, stream>>>(mem, ws_wo, o_ww, o_mem);
  k_link      <<<dim3(Bb*Nn*Nn/1024), dim3(256), 0, stream>>>(link, o_ww, prec, o_link);
  k_polval    <<<dim3(Bb*19/4),    dim3(256), 0, stream>>>(o_h, Wp, bp, Wv, bv, o_logits, o_value);
}

// Round 4
// 345.177 us; speedup vs baseline: 1.3618x; 1.0324x over previous
//
#include <hip/hip_runtime.h>
#include <math.h>

constexpr int Bb = 64, Nn = 512, Vv = 64, Hh = 512, Rr = 4, Aa = 18, INp = 128, KTOP = 32;
constexpr int CIN = 384;   // IN + R*V
constexpr int WOUT = 195;  // 3V+3
#define EPSf 1e-8f

__device__ __forceinline__ float sigmoidf(float x){ return 1.f/(1.f+expf(-x)); }
__device__ __forceinline__ float softplusf(float x){ return (x>20.f)? x : log1pf(expf(x)); }
__device__ __forceinline__ float wave_reduce(float v){
  #pragma unroll
  for(int o=32;o>0;o>>=1) v += __shfl_down(v, o, 64);
  return v;
}

// ---- 1. ro = W_read @ h + b_read ; one wave per (b, p) output, p in [0,272) ----
__global__ void k_read_proj(const float* __restrict__ Wr, const float* __restrict__ br,
                            const float* __restrict__ h, float* __restrict__ ro) {
  int bid = blockIdx.x;
  int b = bid / 68;
  int p = (bid % 68) * 4 + (threadIdx.x >> 6);   // 0..271
  int lane = threadIdx.x & 63;
  const float* wrow = Wr + p * Hh;
  const float* hb = h + b * Hh;
  float acc = 0.f;
  #pragma unroll
  for (int t = 0; t < 8; ++t) { int k = lane + 64*t; acc += wrow[k] * hb[k]; }
  acc = wave_reduce(acc);
  if (lane == 0) ro[b*272 + p] = acc + br[p];
}

// ---- 2. scores[b,r,n] = softplus(ro[64]) * cos-sim ; wave per (b,n); norms inline ----
__global__ void k_scores(const float* __restrict__ mem, const float* __restrict__ ro,
                         float* __restrict__ scores) {
  int row = blockIdx.x*4 + (threadIdx.x>>6);
  int lane = threadIdx.x & 63;
  int b = row >> 9, n = row & 511;
  float m = mem[row*Vv + lane];
  float mn = wave_reduce(m*m);   // valid on lane 0 only
  #pragma unroll
  for (int r = 0; r < Rr; ++r) {
    const float* rob = ro + b*272 + r*68;
    float kv = rob[lane];
    float s  = wave_reduce(m*kv);
    float k2 = wave_reduce(kv*kv);
    if (lane == 0) {
      float rbeta = softplusf(rob[64]);
      float mnc = fmaxf(sqrtf(mn), EPSf);
      float knc = fmaxf(sqrtf(k2), EPSf);
      scores[(b*Rr + r)*Nn + n] = rbeta * s / (mnc * knc);
    }
  }
}

// ---- 3. exact kth-largest (bitonic desc) + masked softmax -> cw ; block per (b,r) ----
__global__ void k_topk_cw(const float* __restrict__ scores, float* __restrict__ cw) {
  __shared__ float sv[512];
  __shared__ float so[512];
  __shared__ float red[256];
  int br = blockIdx.x;
  int tid = threadIdx.x;
  const float* srow = scores + br*Nn;
  for (int i = tid; i < 512; i += 256) { float v = srow[i]; sv[i]=v; so[i]=v; }
  __syncthreads();
  for (int k = 2; k <= 512; k <<= 1) {
    for (int j = k>>1; j > 0; j >>= 1) {
      for (int i = tid; i < 512; i += 256) {
        int ixj = i ^ j;
        if (ixj > i) {
          float a = sv[i], c = sv[ixj];
          bool descSeg = ((i & k) == 0);
          bool sw = descSeg ? (a < c) : (a > c);
          if (sw) { sv[i]=c; sv[ixj]=a; }
        }
      }
      __syncthreads();
    }
  }
  float kth = sv[KTOP-1];
  float mx = sv[0];
  float lsum = 0.f;
  for (int i = tid; i < 512; i += 256) {
    float v = so[i];
    lsum += (v >= kth) ? expf(v - mx) : 0.f;
  }
  red[tid] = lsum; __syncthreads();
  for (int s2 = 128; s2 > 0; s2 >>= 1) {
    if (tid < s2) red[tid] += red[tid+s2];
    __syncthreads();
  }
  float inv = 1.f / red[0];
  for (int i = tid; i < 512; i += 256) {
    float v = so[i];
    cw[br*Nn + i] = (v >= kth) ? expf(v - mx)*inv : 0.f;
  }
}

// ---- 4. fused fw + bw : single pass over link ; block per (b, 64-row chunk) ----
__global__ void k_fwbw(const float* __restrict__ link, const float* __restrict__ rw,
                       float* __restrict__ fw, float* __restrict__ bwpart) {
  __shared__ float bl[4][4][512];   // [wave][r][j]  32 KB
  int b  = blockIdx.x >> 3;
  int ch = blockIdx.x & 7;
  int wv = threadIdx.x >> 6, lane = threadIdx.x & 63;
  const float* rwb = rw + b*Rr*Nn;
  float rwv[4][8];
  #pragma unroll
  for (int r = 0; r < 4; ++r)
    #pragma unroll
    for (int t = 0; t < 8; ++t) rwv[r][t] = rwb[r*512 + lane + 64*t];
  float bwacc[8][4] = {};
  const float* lb = link + (size_t)b*Nn*Nn;
  int n0 = ch*64 + wv*16;
  for (int i = 0; i < 16; ++i) {
    int n = n0 + i;
    float lk[8];
    #pragma unroll
    for (int t = 0; t < 8; ++t) lk[t] = lb[n*512 + lane + 64*t];
    float s0 = rwb[n], s1 = rwb[512+n], s2 = rwb[1024+n], s3 = rwb[1536+n];
    float f0=0,f1=0,f2=0,f3=0;
    #pragma unroll
    for (int t = 0; t < 8; ++t) {
      float lv = lk[t];
      f0 += lv*rwv[0][t]; f1 += lv*rwv[1][t]; f2 += lv*rwv[2][t]; f3 += lv*rwv[3][t];
      bwacc[t][0] += lv*s0; bwacc[t][1] += lv*s1; bwacc[t][2] += lv*s2; bwacc[t][3] += lv*s3;
    }
    f0 = wave_reduce(f0); f1 = wave_reduce(f1);
    f2 = wave_reduce(f2); f3 = wave_reduce(f3);
    if (lane == 0) {
      fw[(b*Rr+0)*Nn+n] = f0; fw[(b*Rr+1)*Nn+n] = f1;
      fw[(b*Rr+2)*Nn+n] = f2; fw[(b*Rr+3)*Nn+n] = f3;
    }
  }
  #pragma unroll
  for (int t = 0; t < 8; ++t)
    #pragma unroll
    for (int r = 0; r < 4; ++r) bl[wv][r][lane + 64*t] = bwacc[t][r];
  __syncthreads();
  int tid = threadIdx.x;
  #pragma unroll
  for (int q = 0; q < 8; ++q) {
    int idx = q*256 + tid;        // r*512 + j
    int r = idx >> 9, j = idx & 511;
    float v = bl[0][r][j] + bl[1][r][j] + bl[2][r][j] + bl[3][r][j];
    bwpart[((size_t)(ch*Bb + b)*Rr + r)*Nn + j] = v;
  }
}

// ---- 5. w_r, psi, usage_new ; rpi inline; sums bw partials; zeroes ws_rvec ----
__global__ void k_wr_usage(const float* __restrict__ bwpart, const float* __restrict__ cw,
                           const float* __restrict__ fw, const float* __restrict__ ro,
                           const float* __restrict__ usage, const float* __restrict__ wwt,
                           float* __restrict__ out_wr, float* __restrict__ out_usage,
                           float* __restrict__ ws_rvec) {
  int idx = blockIdx.x*256 + threadIdx.x;
  if (idx < Bb*Rr*Vv) ws_rvec[idx] = 0.f;
  int b = idx >> 9, n = idx & 511;
  float psi = 1.f;
  #pragma unroll
  for (int r = 0; r < Rr; ++r) {
    int br = b*Rr + r;
    const float* rob = ro + b*272 + r*68;
    float e0 = rob[65], e1 = rob[66], e2 = rob[67];
    float m = fmaxf(e0, fmaxf(e1, e2));
    float x0 = expf(e0-m), x1 = expf(e1-m), x2 = expf(e2-m);
    float inv = 1.f/(x0+x1+x2);
    float bwv = 0.f;
    #pragma unroll
    for (int chh = 0; chh < 8; ++chh)
      bwv += bwpart[((size_t)(chh*Bb + b)*Rr + r)*Nn + n];
    float w = (x0*bwv + x1*cw[br*Nn+n] + x2*fw[br*Nn+n]) * inv;
    out_wr[br*Nn+n] = w;
    psi *= (1.f - w);
  }
  float u = usage[idx], wt = wwt[idx];
  out_usage[idx] = (u + wt - u*wt) * psi;
}

// ---- 6. rvec[b,r,v] = sum_n w_r[b,r,n]*mem[b,n,v] ; (b, n-chunk) blocks, atomic ----
__global__ void k_rvec(const float* __restrict__ wr, const float* __restrict__ mem,
                       float* __restrict__ rvec) {
  int b = blockIdx.x >> 3;
  int ch = blockIdx.x & 7;
  int r = threadIdx.x >> 6, v = threadIdx.x & 63;
  const float* wrow = wr + (b*Rr + r)*Nn;
  const float* mb = mem + (size_t)b*Nn*Vv;
  float acc = 0.f;
  #pragma unroll 4
  for (int t = 0; t < 64; ++t) {
    int n = ch*64 + t;
    acc += wrow[n] * mb[n*Vv + v];
  }
  atomicAdd(&rvec[(b*Rr+r)*Vv + v], acc);
}

// ---- 7. gates GEMM ; wave computes 4j x 4b register tile ----
__global__ void k_gates(const float* __restrict__ x, const float* __restrict__ rvec,
                        const float* __restrict__ h, const float* __restrict__ Wih,
                        const float* __restrict__ Whh, const float* __restrict__ bih,
                        const float* __restrict__ bhh, float* __restrict__ gates) {
  int gid = blockIdx.x*4 + (threadIdx.x>>6);   // jt*16 + bt
  int lane = threadIdx.x & 63;
  int jt = gid >> 4;    // 0..511
  int bt = gid & 15;    // 0..15
  float acc[4][4] = {};
  #pragma unroll
  for (int t = 0; t < 6; ++t) {
    int k = lane + 64*t;
    float u[4], w[4];
    #pragma unroll
    for (int i = 0; i < 4; ++i) {
      int b = bt*4 + i;
      u[i] = (k < INp) ? x[b*INp + k] : rvec[b*(Rr*Vv) + k - INp];
      w[i] = Wih[(jt*4+i)*CIN + k];
    }
    #pragma unroll
    for (int jj = 0; jj < 4; ++jj)
      #pragma unroll
      for (int bb = 0; bb < 4; ++bb) acc[jj][bb] += w[jj]*u[bb];
  }
  #pragma unroll
  for (int t = 0; t < 8; ++t) {
    int k = lane + 64*t;
    float u[4], w[4];
    #pragma unroll
    for (int i = 0; i < 4; ++i) {
      u[i] = h[(bt*4+i)*Hh + k];
      w[i] = Whh[(jt*4+i)*Hh + k];
    }
    #pragma unroll
    for (int jj = 0; jj < 4; ++jj)
      #pragma unroll
      for (int bb = 0; bb < 4; ++bb) acc[jj][bb] += w[jj]*u[bb];
  }
  #pragma unroll
  for (int jj = 0; jj < 4; ++jj)
    #pragma unroll
    for (int bb = 0; bb < 4; ++bb) {
      float v = wave_reduce(acc[jj][bb]);
      if (lane == 0) {
        int j = jt*4 + jj, b = bt*4 + bb;
        gates[b*(4*Hh) + j] = v + bih[j] + bhh[j];
      }
    }
}

// ---- 8. LSTM elementwise ----
__global__ void k_lstm(const float* __restrict__ gates, const float* __restrict__ c,
                       float* __restrict__ out_h, float* __restrict__ out_c) {
  int idx = blockIdx.x*256 + threadIdx.x;
  int b = idx >> 9, hh = idx & 511;
  const float* g = gates + b*2048;
  float ig = sigmoidf(g[hh]), fg = sigmoidf(g[512+hh]);
  float gg = tanhf(g[1024+hh]), og = sigmoidf(g[1536+hh]);
  float cn = fg * c[idx] + ig * gg;
  float hn = og * tanhf(cn);
  out_c[idx] = cn; out_h[idx] = hn;
}

// ---- 9. wo + policy + value ; wave per (b,o), o in [0,214) ----
__global__ void k_wopol(const float* __restrict__ hn, const float* __restrict__ Ww,
                        const float* __restrict__ bw_, const float* __restrict__ Wp,
                        const float* __restrict__ bp, const float* __restrict__ Wv,
                        const float* __restrict__ bv, float* __restrict__ wo,
                        float* __restrict__ out_logits, float* __restrict__ out_value) {
  int gid = blockIdx.x*4 + (threadIdx.x>>6);
  int lane = threadIdx.x & 63;
  int b = gid / 214, o = gid % 214;
  const float* wrow;
  if (o < WOUT) wrow = Ww + o*Hh;
  else if (o < WOUT + Aa) wrow = Wp + (o-WOUT)*Hh;
  else wrow = Wv;
  const float* hb = hn + b*Hh;
  float acc = 0.f;
  #pragma unroll
  for (int t = 0; t < 8; ++t) { int k = lane+64*t; acc += hb[k]*wrow[k]; }
  acc = wave_reduce(acc);
  if (lane == 0) {
    if (o < WOUT) wo[b*WOUT+o] = acc + bw_[o];
    else if (o < WOUT + Aa) out_logits[b*Aa + (o-WOUT)] = acc + bp[o-WOUT];
    else out_value[b] = acc + bv[0];
  }
}

// ---- 10. wsim scores (scaled) ; wave per (b,n) ; norms inline ----
__global__ void k_wsim(const float* __restrict__ mem, const float* __restrict__ wo,
                       float* __restrict__ wsim) {
  int row = blockIdx.x*4 + (threadIdx.x>>6);
  int lane = threadIdx.x & 63;
  int b = row >> 9;
  const float* wob = wo + b*WOUT;
  float kv = wob[lane];
  float m = mem[row*Vv + lane];
  float s  = wave_reduce(m*kv);
  float mn = wave_reduce(m*m);
  float k2 = wave_reduce(kv*kv);
  if (lane == 0) {
    float wbeta = softplusf(wob[192]);
    wsim[row] = wbeta * s / (fmaxf(sqrtf(mn),EPSf) * fmaxf(sqrtf(k2),EPSf));
  }
}

// ---- 11. softmax(wsim) + allocation sort + write_w + prec_new ; block per b ----
__global__ void k_alloc(const float* __restrict__ usage, const float* __restrict__ wo,
                        const float* __restrict__ wsim, const float* __restrict__ prec,
                        float* __restrict__ out_ww, float* __restrict__ out_prec) {
  __shared__ float uv[512];
  __shared__ int   ui[512];
  __shared__ float cp[512];
  __shared__ float al[512];
  __shared__ float red[256];
  int b = blockIdx.x, tid = threadIdx.x;
  float s0 = wsim[b*Nn + tid], s1 = wsim[b*Nn + tid + 256];
  red[tid] = fmaxf(s0, s1); __syncthreads();
  for (int s2=128; s2>0; s2>>=1){ if (tid<s2) red[tid]=fmaxf(red[tid],red[tid+s2]); __syncthreads(); }
  float mx = red[0]; __syncthreads();
  float e0 = expf(s0-mx), e1 = expf(s1-mx);
  red[tid] = e0+e1; __syncthreads();
  for (int s2=128; s2>0; s2>>=1){ if (tid<s2) red[tid]+=red[tid+s2]; __syncthreads(); }
  float cinv = 1.f/red[0];
  float c0 = e0*cinv, c1 = e1*cinv;
  __syncthreads();
  for (int i = tid; i < 512; i += 256) { uv[i] = usage[b*Nn+i]; ui[i] = i; }
  __syncthreads();
  for (int k = 2; k <= 512; k <<= 1) {
    for (int j = k>>1; j > 0; j >>= 1) {
      for (int i = tid; i < 512; i += 256) {
        int ixj = i ^ j;
        if (ixj > i) {
          float av = uv[i], bv = uv[ixj];
          int ai = ui[i], bi = ui[ixj];
          bool gt = (av > bv) || (av == bv && ai > bi);
          bool asc = ((i & k) == 0);
          bool sw = asc ? gt : !gt;
          if (sw) { uv[i]=bv; uv[ixj]=av; ui[i]=bi; ui[ixj]=ai; }
        }
      }
      __syncthreads();
    }
  }
  for (int i = tid; i < 512; i += 256) cp[i] = uv[i];
  __syncthreads();
  for (int d = 1; d < 512; d <<= 1) {
    float t0 = cp[tid]     * ((tid >= d)     ? cp[tid-d]     : 1.f);
    float t1 = cp[tid+256] * ((tid+256 >= d) ? cp[tid+256-d] : 1.f);
    __syncthreads();
    cp[tid] = t0; cp[tid+256] = t1;
    __syncthreads();
  }
  for (int i = tid; i < 512; i += 256) {
    float pp = (i == 0) ? 1.f : cp[i-1];
    al[ui[i]] = (1.f - uv[i]) * pp;
  }
  __syncthreads();
  float ga = sigmoidf(wo[b*WOUT+193]);
  float gw = sigmoidf(wo[b*WOUT+194]);
  int n0 = tid, n1 = tid+256;
  float wv0 = gw * (ga*al[n0] + (1.f-ga)*c0);
  float wv1 = gw * (ga*al[n1] + (1.f-ga)*c1);
  out_ww[b*Nn+n0] = wv0; out_ww[b*Nn+n1] = wv1;
  red[tid] = wv0 + wv1; __syncthreads();
  for (int s2=128; s2>0; s2>>=1){ if (tid<s2) red[tid]+=red[tid+s2]; __syncthreads(); }
  float wsum = red[0];
  out_prec[b*Nn+n0] = (1.f - wsum)*prec[b*Nn+n0] + wv0;
  out_prec[b*Nn+n1] = (1.f - wsum)*prec[b*Nn+n1] + wv1;
}

// ---- 12. fused link_new + mem_new elementwise, float4 ----
__global__ void k_memlink(const float* __restrict__ link, const float* __restrict__ ww,
                          const float* __restrict__ prec, const float* __restrict__ mem,
                          const float* __restrict__ wo, float* __restrict__ out_link,
                          float* __restrict__ out_mem) {
  int bid = blockIdx.x;
  if (bid < 16384) {
    int idx4 = bid*256 + threadIdx.x;
    int base = idx4*4;
    int b = base >> 18;
    int rem = base & 262143;
    int i = rem >> 9;
    int j0 = rem & 511;
    float wi = ww[b*Nn + i];
    float fi = 1.f - wi;
    float4 lv = *(const float4*)(link + base);
    float4 wj = *(const float4*)(ww + b*Nn + j0);
    float4 pj = *(const float4*)(prec + b*Nn + j0);
    float4 o;
    o.x = fi*(1.f-wj.x)*lv.x + wi*pj.x;
    o.y = fi*(1.f-wj.y)*lv.y + wi*pj.y;
    o.z = fi*(1.f-wj.z)*lv.z + wi*pj.z;
    o.w = fi*(1.f-wj.w)*lv.w + wi*pj.w;
    if (i >= j0 && i < j0+4) {
      if (i == j0) o.x = 0.f;
      else if (i == j0+1) o.y = 0.f;
      else if (i == j0+2) o.z = 0.f;
      else o.w = 0.f;
    }
    *(float4*)(out_link + base) = o;
  } else {
    int idx4 = (bid - 16384)*256 + threadIdx.x;
    int base = idx4*4;
    int b = base >> 15;
    int rem = base & 32767;
    int n = rem >> 6;
    int v0 = rem & 63;
    float w = ww[b*Nn + n];
    const float* wob = wo + b*WOUT;
    float4 m = *(const float4*)(mem + base);
    float4 o;
    float e, a;
    e = sigmoidf(wob[64+v0+0]); a = tanhf(wob[128+v0+0]); o.x = m.x*(1.f-w*e)+w*a;
    e = sigmoidf(wob[64+v0+1]); a = tanhf(wob[128+v0+1]); o.y = m.y*(1.f-w*e)+w*a;
    e = sigmoidf(wob[64+v0+2]); a = tanhf(wob[128+v0+2]); o.z = m.z*(1.f-w*e)+w*a;
    e = sigmoidf(wob[64+v0+3]); a = tanhf(wob[128+v0+3]); o.w = m.w*(1.f-w*e)+w*a;
    *(float4*)(out_mem + base) = o;
  }
}

extern "C" void kernel_launch(void* const* d_in, const int* in_sizes, int n_in,
                              void* d_out, int out_size, void* d_ws, size_t ws_size,
                              hipStream_t stream) {
  const float* x    = (const float*)d_in[0];
  const float* h    = (const float*)d_in[1];
  const float* c    = (const float*)d_in[2];
  const float* mem  = (const float*)d_in[3];
  const float* rw   = (const float*)d_in[4];
  const float* wwt  = (const float*)d_in[5];
  const float* usage= (const float*)d_in[6];
  const float* link = (const float*)d_in[7];
  const float* prec = (const float*)d_in[8];
  const float* Wih  = (const float*)d_in[9];
  const float* Whh  = (const float*)d_in[10];
  const float* bih  = (const float*)d_in[11];
  const float* bhh  = (const float*)d_in[12];
  const float* Wr   = (const float*)d_in[13];
  const float* br   = (const float*)d_in[14];
  const float* Ww   = (const float*)d_in[15];
  const float* bw_  = (const float*)d_in[16];
  const float* Wp   = (const float*)d_in[17];
  const float* bp   = (const float*)d_in[18];
  const float* Wv   = (const float*)d_in[19];
  const float* bv   = (const float*)d_in[20];

  float* out = (float*)d_out;
  float* o_logits = out + 0;
  float* o_value  = out + 1152;
  float* o_h      = out + 1216;
  float* o_c      = out + 33984;
  float* o_mem    = out + 66752;
  float* o_wr     = out + 2163904;
  float* o_ww     = out + 2294976;
  float* o_usage  = out + 2327744;
  float* o_link   = out + 2360512;
  float* o_prec   = out + 19137728;

  float* ws = (float*)d_ws;
  float* ws_ro     = ws;             // 17408
  float* ws_sc     = ws + 17408;     // 131072
  float* ws_cw     = ws + 148480;    // 131072
  float* ws_fw     = ws + 279552;    // 131072
  float* ws_bwpart = ws + 410624;    // 1048576 (8 chunks x 64 b x 4 r x 512 j)
  float* ws_rvec   = ws + 1459200;   // 16384 (zeroed by k_wr_usage, atomic acc)
  float* ws_gates  = ws + 1475584;   // 131072
  float* ws_wo     = ws + 1606656;   // 12480
  float* ws_wsim   = ws + 1619136;   // 32768  (end ~6.6 MB)

  k_read_proj <<<dim3(Bb*68),        dim3(256), 0, stream>>>(Wr, br, h, ws_ro);
  k_scores    <<<dim3(Bb*Nn/4),      dim3(256), 0, stream>>>(mem, ws_ro, ws_sc);
  k_topk_cw   <<<dim3(Bb*Rr),        dim3(256), 0, stream>>>(ws_sc, ws_cw);
  k_fwbw      <<<dim3(Bb*8),         dim3(256), 0, stream>>>(link, rw, ws_fw, ws_bwpart);
  k_wr_usage  <<<dim3(Bb*Nn/256),    dim3(256), 0, stream>>>(ws_bwpart, ws_cw, ws_fw, ws_ro, usage, wwt, o_wr, o_usage, ws_rvec);
  k_rvec      <<<dim3(Bb*8),         dim3(256), 0, stream>>>(o_wr, mem, ws_rvec);
  k_gates     <<<dim3(2048),         dim3(256), 0, stream>>>(x, ws_rvec, h, Wih, Whh, bih, bhh, ws_gates);
  k_lstm      <<<dim3(Bb*Hh/256),    dim3(256), 0, stream>>>(ws_gates, c, o_h, o_c);
  k_wopol     <<<dim3(Bb*214/4),     dim3(256), 0, stream>>>(o_h, Ww, bw_, Wp, bp, Wv, bv, ws_wo, o_logits, o_value);
  k_wsim      <<<dim3(Bb*Nn/4),      dim3(256), 0, stream>>>(mem, ws_wo, ws_wsim);
  k_alloc     <<<dim3(Bb),           dim3(256), 0, stream>>>(usage, ws_wo, ws_wsim, prec, o_ww, o_prec);
  k_memlink   <<<dim3(16384+2048),   dim3(256), 0, stream>>>(link, o_ww, prec, mem, ws_wo, o_link, o_mem);
}